// Round 9
// baseline (190.466 us; speedup 1.0000x reference)
//
#include <hip/hip_runtime.h>
#include <hip/hip_bf16.h>
#include <hip/hip_fp16.h>
#include <cstdint>

typedef __attribute__((ext_vector_type(4))) float f32x4;
typedef __attribute__((ext_vector_type(8))) short s16x8;

#define DEVI static __device__ __forceinline__

constexpr int Bc = 8, Tc = 2048, Sc = 8, Dc = 256;
constexpr int Mc = Bc * Tc * Sc;  // 131072 rows

// plain-cast f32->bf16 (RNE): compiler packs pairs into v_cvt_pk_bf16_f32
DEVI unsigned short f2bf(float x) {
  return __bfloat16_as_ushort(__float2bfloat16(x));
}

DEVI f32x4 mfma16(s16x8 a, s16x8 b, f32x4 c) {
  return __builtin_amdgcn_mfma_f32_16x16x32_bf16(a, b, c, 0, 0, 0);
}

// async global->LDS, 16B per lane (dest must be wave-uniform base + lane*16)
DEVI void gld16(const void* g, void* l) {
  __builtin_amdgcn_global_load_lds(
      (const __attribute__((address_space(1))) unsigned int*)g,
      (__attribute__((address_space(3))) unsigned int*)l, 16, 0, 0);
}

// ---------------- x f32 -> bf16 ----------------
__global__ void cvt_x_k(const float* __restrict__ in, unsigned short* __restrict__ out, int n) {
  int i = (blockIdx.x * blockDim.x + threadIdx.x) * 8;
  int stride = gridDim.x * blockDim.x * 8;
  for (; i < n; i += stride) {
    f32x4 a = *(const f32x4*)(in + i);
    f32x4 b = *(const f32x4*)(in + i + 4);
    s16x8 o;
    o[0] = (short)f2bf(a[0]); o[1] = (short)f2bf(a[1]);
    o[2] = (short)f2bf(a[2]); o[3] = (short)f2bf(a[3]);
    o[4] = (short)f2bf(b[0]); o[5] = (short)f2bf(b[1]);
    o[6] = (short)f2bf(b[2]); o[7] = (short)f2bf(b[3]);
    *(s16x8*)(out + i) = o;
  }
}

// ---------------- weight transpose+convert (both W in one kernel) ----------------
__global__ void cvtW_k(const float* __restrict__ Win, const float* __restrict__ Wout,
                       unsigned short* __restrict__ wtin, unsigned short* __restrict__ wtout) {
  int tid = blockIdx.x * blockDim.x + threadIdx.x;
  if (tid < 512 * 256) {
    int c = tid >> 8, r = tid & 255;
    wtin[tid] = f2bf(Win[r * 512 + c]);
  } else {
    int t = tid - 512 * 256;
    int c = t >> 8, r = t & 255;
    wtout[t] = f2bf(Wout[r * 256 + c]);
  }
}

// ---------------- fused GEMM1 + activation + PARALLEL scan ----------------
// Block = (b, s, dq): 256 blocks x 512 threads (8 waves). W_in cols for this dq
// resident in LDS. Per 64-t chunk: GEMM+act -> abuf; wave w composes its 8
// t-steps into (A_w,B_w) [lane=d]; all waves redundantly prefix-walk the 8
// segments (carry stt identical across waves); wave w applies its 8 steps from
// registers and stores y. No serial-wave bottleneck.
__global__ __launch_bounds__(512, 1) void g1scan_k(
    const unsigned short* __restrict__ xb,   // [M][256] bf16
    const unsigned short* __restrict__ wt,   // [512][256] bf16 = W_in^T
    const float* __restrict__ bias,          // [512]
    unsigned short* __restrict__ yb)         // [M][256] bf16
{
  __shared__ unsigned short As[2][8 * 64 * 32];   // 2 x 32 KB, panel p = K [p*32,+32)
  __shared__ unsigned short Ws[8 * 128 * 32];     // 64 KB, rows 0..63 gate, 64..127 cand
  __shared__ unsigned int   abuf[64 * 64];        // 16 KB: [t_local][d_local] (a,b) half2
  __shared__ float segA[8][64], segB[8][64];      // 4 KB segment compositions

  int bid = blockIdx.x;
  int b = bid >> 5, s = (bid >> 2) & 7, dq = bid & 3;
  int tid = threadIdx.x;
  int lane = tid & 63, wave = tid >> 6;
  int rg = wave >> 2, cg = wave & 3;

  const short* xs = (const short*)xb;
  const short* wsrc = (const short*)wt;
  size_t rowbase = (size_t)b * 16384 + s;   // global row = rowbase + t*8

  // stage W once: 4096 16B chunks; j -> panel j>>9, row (j>>2)&127, 16B sub (j&3)
  #pragma unroll
  for (int q = 0; q < 8; ++q) {
    int j = q * 512 + tid;
    int p = j >> 9, rem = j & 511, r = rem >> 2, cc = rem & 3;
    int wrow = (r < 64) ? (dq * 64 + r) : (256 + dq * 64 + (r - 64));
    gld16(wsrc + (size_t)wrow * 256 + p * 32 + cc * 8,
          (unsigned short*)Ws + (size_t)j * 8);
  }

  auto STAGE_A = [&](int buf, int t0) {
    #pragma unroll
    for (int q = 0; q < 4; ++q) {
      int j = q * 512 + tid;
      int p = j >> 8, rem = j & 255, r = rem >> 2, cc = rem & 3;
      size_t grow = rowbase + (size_t)(t0 + r) * 8;
      gld16(xs + grow * 256 + p * 32 + cc * 8,
            (unsigned short*)As + (size_t)buf * 16384 + (size_t)j * 8);
    }
  };

  STAGE_A(0, 0);

  int cl = cg * 16 + (lane & 15);          // d-local col for this thread
  float bg = bias[dq * 64 + cl];
  float bc = bias[256 + dq * 64 + cl];
  int kg = (lane >> 4) * 8;

  float stt = 0.f;   // scan carry for d = dq*64 + lane (identical across waves)

  __syncthreads();

  for (int ch = 0; ch < 32; ++ch) {
    int cur = ch & 1;
    if (ch < 31) STAGE_A(cur ^ 1, (ch + 1) * 64);

    f32x4 accG[2] = {}, accC[2] = {};
    #pragma unroll
    for (int kf = 0; kf < 8; ++kf) {
      s16x8 aF[2], bG, bC;
      #pragma unroll
      for (int mf = 0; mf < 2; ++mf)
        aF[mf] = *(const s16x8*)((unsigned short*)As + (size_t)cur * 16384 + kf * 2048 +
                                 (rg * 32 + mf * 16 + (lane & 15)) * 32 + kg);
      bG = *(const s16x8*)((unsigned short*)Ws + kf * 4096 + cl * 32 + kg);
      bC = *(const s16x8*)((unsigned short*)Ws + kf * 4096 + (64 + cl) * 32 + kg);
      #pragma unroll
      for (int mf = 0; mf < 2; ++mf) {
        accG[mf] = mfma16(aF[mf], bG, accG[mf]);
        accC[mf] = mfma16(aF[mf], bC, accC[mf]);
      }
    }

    // activation in-register (gate & cand of same (row,col) live in same thread)
    unsigned pk[2][4];
    #pragma unroll
    for (int mf = 0; mf < 2; ++mf)
      #pragma unroll
      for (int r = 0; r < 4; ++r) {
        float g = accG[mf][r] + bg;
        float c = accC[mf][r] + bc;
        float alpha = 1.f / (1.f + __expf(-g));
        float e2 = __expf(2.f * c);
        float th = 1.f - 2.f / (e2 + 1.f);   // tanh(c), stable for +/-inf
        __half2 h;
        h.x = __float2half(1.f - alpha);
        h.y = __float2half(alpha * th);
        pk[mf][r] = *(unsigned*)&h;
      }

    __syncthreads();   // prev chunk's apply-phase abuf reads complete

    #pragma unroll
    for (int mf = 0; mf < 2; ++mf)
      #pragma unroll
      for (int r = 0; r < 4; ++r) {
        int row = rg * 32 + mf * 16 + (lane >> 4) * 4 + r;
        abuf[row * 64 + cl] = pk[mf][r];
      }

    __syncthreads();   // abuf ready

    // --- parallel scan: wave w owns t-steps [w*8, w*8+8) ---
    float av[8], bv[8];
    float A = 1.f, Bv = 0.f;
    #pragma unroll
    for (int u = 0; u < 8; ++u) {
      unsigned vv = abuf[(wave * 8 + u) * 64 + lane];
      __half2 h = *(__half2*)&vv;
      av[u] = __half2float(h.x);
      bv[u] = __half2float(h.y);
      A = av[u] * A;
      Bv = fmaf(av[u], Bv, bv[u]);
    }
    segA[wave][lane] = A;
    segB[wave][lane] = Bv;

    __syncthreads();   // segments ready

    // redundant prefix walk over 8 segments (identical result on every wave)
    float sin = stt, s_w = stt;
    #pragma unroll
    for (int w2 = 0; w2 < 8; ++w2) {
      if (w2 == wave) s_w = sin;
      sin = fmaf(segA[w2][lane], sin, segB[w2][lane]);
    }
    stt = sin;         // carry into next chunk

    // apply own segment from registers, store y
    size_t ybase = (rowbase + (size_t)(ch * 64 + wave * 8) * 8) * 256 + dq * 64 + lane;
    float sv = s_w;
    #pragma unroll
    for (int u = 0; u < 8; ++u) {
      sv = fmaf(av[u], sv, bv[u]);
      yb[ybase + (size_t)u * 8 * 256] = f2bf(sv);
    }
  }
}

// ---------------- GEMM2: out = y@W_out + b_out ----------------
// BK=64 as two [128][32] sub-panels. grid 2048 = 1024 mtiles x 2 ctiles.
__global__ __launch_bounds__(256, 2) void gemm2_k(
    const unsigned short* __restrict__ yb,   // [M][256] bf16
    const unsigned short* __restrict__ wt,   // [256][256] bf16 = W_out^T
    const float* __restrict__ bias,          // [256]
    float* __restrict__ out)
{
  __shared__ unsigned short As[2][2][128 * 32];
  __shared__ unsigned short Bs[2][2][128 * 32];

  int bid = blockIdx.x;
  int swz = (bid & 7) * 256 + (bid >> 3);
  int mtile = swz >> 1, ctile = swz & 1;
  int tid = threadIdx.x;
  int lane = tid & 63, wave = tid >> 6;
  int wr = wave >> 1, wc = wave & 1;

  const short* ys = (const short*)yb;
  const short* wsrc = (const short*)wt;

  auto STAGE = [&](int buf, int k0) {
    unsigned short* Ad = &As[buf][0][0];
    unsigned short* Bd = &Bs[buf][0][0];
    #pragma unroll
    for (int q = 0; q < 4; ++q) {
      int j = q * 256 + tid;
      int p = j >> 9, r = (j >> 2) & 127, cc = j & 3;
      int koff = k0 + p * 32 + cc * 8;
      gld16(ys + (size_t)(mtile * 128 + r) * 256 + koff, Ad + (size_t)j * 8);
      gld16(wsrc + (size_t)(ctile * 128 + r) * 256 + koff, Bd + (size_t)j * 8);
    }
  };

  f32x4 acc[4][4] = {};

  STAGE(0, 0);
  __syncthreads();
  #pragma unroll
  for (int kk = 0; kk < 4; ++kk) {
    int cur = kk & 1;
    if (kk < 3) STAGE(cur ^ 1, (kk + 1) * 64);
    int kg = (lane >> 4) * 8;
    #pragma unroll
    for (int ks = 0; ks < 2; ++ks) {
      s16x8 aF[4], bF[4];
      #pragma unroll
      for (int mf = 0; mf < 4; ++mf)
        aF[mf] = *(const s16x8*)&As[cur][ks][(wr * 64 + mf * 16 + (lane & 15)) * 32 + kg];
      #pragma unroll
      for (int nf = 0; nf < 4; ++nf)
        bF[nf] = *(const s16x8*)&Bs[cur][ks][(wc * 64 + nf * 16 + (lane & 15)) * 32 + kg];
      #pragma unroll
      for (int mf = 0; mf < 4; ++mf)
        #pragma unroll
        for (int nf = 0; nf < 4; ++nf)
          acc[mf][nf] = mfma16(aF[mf], bF[nf], acc[mf][nf]);
    }
    if (kk < 3) __syncthreads();
  }

  int orow0 = mtile * 128 + wr * 64 + (lane >> 4) * 4;
  #pragma unroll
  for (int nf = 0; nf < 4; ++nf) {
    int col = ctile * 128 + wc * 64 + nf * 16 + (lane & 15);
    float bo = bias[col];
    #pragma unroll
    for (int mf = 0; mf < 4; ++mf) {
      #pragma unroll
      for (int r = 0; r < 4; ++r) {
        int row = orow0 + mf * 16 + r;
        out[(size_t)row * 256 + col] = acc[mf][nf][r] + bo;
      }
    }
  }
}

// ---------------- host ----------------
extern "C" void kernel_launch(void* const* d_in, const int* in_sizes, int n_in,
                              void* d_out, int out_size, void* d_ws, size_t ws_size,
                              hipStream_t stream)
{
  const float* x    = (const float*)d_in[0];
  const float* Win  = (const float*)d_in[1];
  const float* bin  = (const float*)d_in[2];
  const float* Wout = (const float*)d_in[3];
  const float* bout = (const float*)d_in[4];
  float* out = (float*)d_out;
  char* ws = (char*)d_ws;

  // ws layout: Wt_in (256 KiB) | Wt_out (128 KiB) | yb (64 MiB) | xb (64 MiB)
  unsigned short* wtin  = (unsigned short*)(ws);
  unsigned short* wtout = (unsigned short*)(ws + 262144);
  unsigned short* yb    = (unsigned short*)(ws + 393216);
  unsigned short* xb    = (unsigned short*)(ws + 393216 + (size_t)Mc * 256 * 2);

  cvt_x_k<<<1024, 256, 0, stream>>>(x, xb, Mc * 256);
  cvtW_k<<<768, 256, 0, stream>>>(Win, Wout, wtin, wtout);
  g1scan_k<<<256, 512, 0, stream>>>(xb, wtin, bin, yb);
  gemm2_k<<<2048, 256, 0, stream>>>(yb, wtout, bout, out);
}

// Round 10
// 189.218 us; speedup vs baseline: 1.0066x; 1.0066x over previous
//
#include <hip/hip_runtime.h>
#include <hip/hip_bf16.h>
#include <hip/hip_fp16.h>
#include <cstdint>

typedef __attribute__((ext_vector_type(4))) float f32x4;
typedef __attribute__((ext_vector_type(8))) short s16x8;

#define DEVI static __device__ __forceinline__

constexpr int Bc = 8, Tc = 2048, Sc = 8, Dc = 256;
constexpr int Mc = Bc * Tc * Sc;  // 131072 rows

// plain-cast f32->bf16 (RNE): compiler packs pairs into v_cvt_pk_bf16_f32
DEVI unsigned short f2bf(float x) {
  return __bfloat16_as_ushort(__float2bfloat16(x));
}

DEVI f32x4 mfma16(s16x8 a, s16x8 b, f32x4 c) {
  return __builtin_amdgcn_mfma_f32_16x16x32_bf16(a, b, c, 0, 0, 0);
}

// async global->LDS, 16B per lane (dest must be wave-uniform base + lane*16)
DEVI void gld16(const void* g, void* l) {
  __builtin_amdgcn_global_load_lds(
      (const __attribute__((address_space(1))) unsigned int*)g,
      (__attribute__((address_space(3))) unsigned int*)l, 16, 0, 0);
}

// ---------------- x f32 -> bf16 ----------------
__global__ void cvt_x_k(const float* __restrict__ in, unsigned short* __restrict__ out, int n) {
  int i = (blockIdx.x * blockDim.x + threadIdx.x) * 8;
  int stride = gridDim.x * blockDim.x * 8;
  for (; i < n; i += stride) {
    f32x4 a = *(const f32x4*)(in + i);
    f32x4 b = *(const f32x4*)(in + i + 4);
    s16x8 o;
    o[0] = (short)f2bf(a[0]); o[1] = (short)f2bf(a[1]);
    o[2] = (short)f2bf(a[2]); o[3] = (short)f2bf(a[3]);
    o[4] = (short)f2bf(b[0]); o[5] = (short)f2bf(b[1]);
    o[6] = (short)f2bf(b[2]); o[7] = (short)f2bf(b[3]);
    *(s16x8*)(out + i) = o;
  }
}

// ---------------- weight transpose+convert (both W in one kernel) ----------------
__global__ void cvtW_k(const float* __restrict__ Win, const float* __restrict__ Wout,
                       unsigned short* __restrict__ wtin, unsigned short* __restrict__ wtout) {
  int tid = blockIdx.x * blockDim.x + threadIdx.x;
  if (tid < 512 * 256) {
    int c = tid >> 8, r = tid & 255;
    wtin[tid] = f2bf(Win[r * 512 + c]);
  } else {
    int t = tid - 512 * 256;
    int c = t >> 8, r = t & 255;
    wtout[t] = f2bf(Wout[r * 256 + c]);
  }
}

// ---------------- fused GEMM1 + activation + parallel scan ----------------
// Block = (b, s, dq): 256 blocks x 512 threads (8 waves).
// W fragments HOISTED TO REGISTERS (64 VGPR) after a one-time LDS stage; the Ws
// LDS region is then reused for abuf[2] + seg[2] (total LDS = 128 KB).
// 2 barriers/chunk; STAGE of chunk ch+2 is issued after B2 so its vmcnt(0)
// drain (next chunk's B1) has ~full-chunk cover. Staging pointers incremental.
__global__ __launch_bounds__(512, 1) void g1scan_k(
    const unsigned short* __restrict__ xb,   // [M][256] bf16
    const unsigned short* __restrict__ wt,   // [512][256] bf16 = W_in^T
    const float* __restrict__ bias,          // [512]
    unsigned short* __restrict__ yb)         // [M][256] bf16
{
  __shared__ unsigned short As[2][8 * 64 * 32];   // 2 x 32 KB, panel p = K [p*32,+32)
  __shared__ unsigned char pool[65536];           // Ws during init; abuf[2]+seg[2] after

  unsigned short* Ws = (unsigned short*)pool;     // [8 panels][128 rows][32]
  unsigned* abuf = (unsigned*)pool;               // [2][64][64] (a,b) half2
  float* segAp = (float*)(pool + 32768);          // [2][8][64]
  float* segBp = (float*)(pool + 40960);          // [2][8][64]

  int bid = blockIdx.x;
  int b = bid >> 5, s = (bid >> 2) & 7, dq = bid & 3;
  int tid = threadIdx.x;
  int lane = tid & 63, wave = tid >> 6;
  int rg = wave >> 2, cg = wave & 3;

  const short* xs = (const short*)xb;
  const short* wsrc = (const short*)wt;
  size_t rowbase = (size_t)b * 16384 + s;   // global row = rowbase + t*8

  // ---- stage W once: 4096 16B chunks ----
  #pragma unroll
  for (int q = 0; q < 8; ++q) {
    int j = q * 512 + tid;
    int p = j >> 9, rem = j & 511, r = rem >> 2, cc = rem & 3;
    int wrow = (r < 64) ? (dq * 64 + r) : (256 + dq * 64 + (r - 64));
    gld16(wsrc + (size_t)wrow * 256 + p * 32 + cc * 8, Ws + (size_t)j * 8);
  }

  // ---- precompute incremental A-staging pointers (t0 = 0) ----
  const short* pA[4];
  int ldso[4];
  #pragma unroll
  for (int q = 0; q < 4; ++q) {
    int j = q * 512 + tid;
    int p = j >> 8, rem = j & 255, r = rem >> 2, cc = rem & 3;
    pA[q] = xs + (rowbase + (size_t)r * 8) * 256 + p * 32 + cc * 8;
    ldso[q] = j * 8;                         // short offset into As buffer
  }
  const size_t ASTRIDE = (size_t)64 * 8 * 256;   // shorts per 64-t chunk

  // prologue: stage chunks 0 and 1
  #pragma unroll
  for (int q = 0; q < 4; ++q) gld16(pA[q], (unsigned short*)As[0] + ldso[q]);
  #pragma unroll
  for (int q = 0; q < 4; ++q) gld16(pA[q] + ASTRIDE, (unsigned short*)As[1] + ldso[q]);
  #pragma unroll
  for (int q = 0; q < 4; ++q) pA[q] += 2 * ASTRIDE;   // next stage = chunk 2

  int cl = cg * 16 + (lane & 15);          // d-local col for this thread
  float bg = bias[dq * 64 + cl];
  float bc = bias[256 + dq * 64 + cl];
  int kg = (lane >> 4) * 8;

  __syncthreads();   // Ws + As[0..1] resident

  // ---- hoist W fragments to registers (chunk-invariant) ----
  s16x8 bGr[8], bCr[8];
  #pragma unroll
  for (int kf = 0; kf < 8; ++kf) {
    bGr[kf] = *(const s16x8*)(Ws + kf * 4096 + cl * 32 + kg);
    bCr[kf] = *(const s16x8*)(Ws + kf * 4096 + (64 + cl) * 32 + kg);
  }
  __syncthreads();   // Ws reads done -> pool reusable as abuf/seg

  float stt = 0.f;   // scan carry for d = dq*64 + lane (identical across waves)

  for (int ch = 0; ch < 32; ++ch) {
    int cur = ch & 1;
    const unsigned short* Ab = (const unsigned short*)As[cur];

    // ---- GEMM (W from registers, A from LDS) ----
    f32x4 accG[2] = {}, accC[2] = {};
    #pragma unroll
    for (int kf = 0; kf < 8; ++kf) {
      s16x8 aF[2];
      #pragma unroll
      for (int mf = 0; mf < 2; ++mf)
        aF[mf] = *(const s16x8*)(Ab + kf * 2048 +
                                 (rg * 32 + mf * 16 + (lane & 15)) * 32 + kg);
      #pragma unroll
      for (int mf = 0; mf < 2; ++mf) {
        accG[mf] = mfma16(aF[mf], bGr[kf], accG[mf]);
        accC[mf] = mfma16(aF[mf], bCr[kf], accC[mf]);
      }
    }

    // ---- activation in-register ----
    unsigned pk[2][4];
    #pragma unroll
    for (int mf = 0; mf < 2; ++mf)
      #pragma unroll
      for (int r = 0; r < 4; ++r) {
        float g = accG[mf][r] + bg;
        float c = accC[mf][r] + bc;
        float alpha = 1.f / (1.f + __expf(-g));
        float e2 = __expf(2.f * c);
        float th = 1.f - 2.f / (e2 + 1.f);   // tanh(c), stable for +/-inf
        __half2 h;
        h.x = __float2half(1.f - alpha);
        h.y = __float2half(alpha * th);
        pk[mf][r] = *(unsigned*)&h;
      }

    unsigned* ab_c = abuf + cur * 4096;
    #pragma unroll
    for (int mf = 0; mf < 2; ++mf)
      #pragma unroll
      for (int r = 0; r < 4; ++r) {
        int row = rg * 32 + mf * 16 + (lane >> 4) * 4 + r;
        ab_c[row * 64 + cl] = pk[mf][r];
      }

    __syncthreads();   // B1: abuf[cur] ready (also drains stage issued last iter)

    // ---- compose: wave w owns t-steps [w*8, w*8+8) ----
    float av[8], bv[8];
    float A = 1.f, Bv = 0.f;
    #pragma unroll
    for (int u = 0; u < 8; ++u) {
      unsigned vv = ab_c[(wave * 8 + u) * 64 + lane];
      __half2 h = *(__half2*)&vv;
      av[u] = __half2float(h.x);
      bv[u] = __half2float(h.y);
      A = av[u] * A;
      Bv = fmaf(av[u], Bv, bv[u]);
    }
    segAp[cur * 512 + wave * 64 + lane] = A;
    segBp[cur * 512 + wave * 64 + lane] = Bv;

    __syncthreads();   // B2: segments ready

    // ---- issue next-next chunk's staging (drained at NEXT chunk's B1) ----
    if (ch + 2 < 32) {
      #pragma unroll
      for (int q = 0; q < 4; ++q) gld16(pA[q], (unsigned short*)As[cur] + ldso[q]);
      #pragma unroll
      for (int q = 0; q < 4; ++q) pA[q] += ASTRIDE;
    }

    // ---- redundant prefix walk (identical on every wave) + apply ----
    float sin = stt, s_w = stt;
    #pragma unroll
    for (int w2 = 0; w2 < 8; ++w2) {
      if (w2 == wave) s_w = sin;
      sin = fmaf(segAp[cur * 512 + w2 * 64 + lane], sin,
                 segBp[cur * 512 + w2 * 64 + lane]);
    }
    stt = sin;         // carry into next chunk

    size_t ybase = (rowbase + (size_t)(ch * 64 + wave * 8) * 8) * 256 + dq * 64 + lane;
    float sv = s_w;
    #pragma unroll
    for (int u = 0; u < 8; ++u) {
      sv = fmaf(av[u], sv, bv[u]);
      yb[ybase + (size_t)u * 8 * 256] = f2bf(sv);
    }
  }
}

// ---------------- GEMM2: out = y@W_out + b_out ----------------
// BK=64 as two [128][32] sub-panels. grid 2048 = 1024 mtiles x 2 ctiles.
__global__ __launch_bounds__(256, 2) void gemm2_k(
    const unsigned short* __restrict__ yb,   // [M][256] bf16
    const unsigned short* __restrict__ wt,   // [256][256] bf16 = W_out^T
    const float* __restrict__ bias,          // [256]
    float* __restrict__ out)
{
  __shared__ unsigned short As[2][2][128 * 32];
  __shared__ unsigned short Bs[2][2][128 * 32];

  int bid = blockIdx.x;
  int swz = (bid & 7) * 256 + (bid >> 3);
  int mtile = swz >> 1, ctile = swz & 1;
  int tid = threadIdx.x;
  int lane = tid & 63, wave = tid >> 6;
  int wr = wave >> 1, wc = wave & 1;

  const short* ys = (const short*)yb;
  const short* wsrc = (const short*)wt;

  auto STAGE = [&](int buf, int k0) {
    unsigned short* Ad = &As[buf][0][0];
    unsigned short* Bd = &Bs[buf][0][0];
    #pragma unroll
    for (int q = 0; q < 4; ++q) {
      int j = q * 256 + tid;
      int p = j >> 9, r = (j >> 2) & 127, cc = j & 3;
      int koff = k0 + p * 32 + cc * 8;
      gld16(ys + (size_t)(mtile * 128 + r) * 256 + koff, Ad + (size_t)j * 8);
      gld16(wsrc + (size_t)(ctile * 128 + r) * 256 + koff, Bd + (size_t)j * 8);
    }
  };

  f32x4 acc[4][4] = {};

  STAGE(0, 0);
  __syncthreads();
  #pragma unroll
  for (int kk = 0; kk < 4; ++kk) {
    int cur = kk & 1;
    if (kk < 3) STAGE(cur ^ 1, (kk + 1) * 64);
    int kg = (lane >> 4) * 8;
    #pragma unroll
    for (int ks = 0; ks < 2; ++ks) {
      s16x8 aF[4], bF[4];
      #pragma unroll
      for (int mf = 0; mf < 4; ++mf)
        aF[mf] = *(const s16x8*)&As[cur][ks][(wr * 64 + mf * 16 + (lane & 15)) * 32 + kg];
      #pragma unroll
      for (int nf = 0; nf < 4; ++nf)
        bF[nf] = *(const s16x8*)&Bs[cur][ks][(wc * 64 + nf * 16 + (lane & 15)) * 32 + kg];
      #pragma unroll
      for (int mf = 0; mf < 4; ++mf)
        #pragma unroll
        for (int nf = 0; nf < 4; ++nf)
          acc[mf][nf] = mfma16(aF[mf], bF[nf], acc[mf][nf]);
    }
    if (kk < 3) __syncthreads();
  }

  int orow0 = mtile * 128 + wr * 64 + (lane >> 4) * 4;
  #pragma unroll
  for (int nf = 0; nf < 4; ++nf) {
    int col = ctile * 128 + wc * 64 + nf * 16 + (lane & 15);
    float bo = bias[col];
    #pragma unroll
    for (int mf = 0; mf < 4; ++mf) {
      #pragma unroll
      for (int r = 0; r < 4; ++r) {
        int row = orow0 + mf * 16 + r;
        out[(size_t)row * 256 + col] = acc[mf][nf][r] + bo;
      }
    }
  }
}

// ---------------- host ----------------
extern "C" void kernel_launch(void* const* d_in, const int* in_sizes, int n_in,
                              void* d_out, int out_size, void* d_ws, size_t ws_size,
                              hipStream_t stream)
{
  const float* x    = (const float*)d_in[0];
  const float* Win  = (const float*)d_in[1];
  const float* bin  = (const float*)d_in[2];
  const float* Wout = (const float*)d_in[3];
  const float* bout = (const float*)d_in[4];
  float* out = (float*)d_out;
  char* ws = (char*)d_ws;

  // ws layout: Wt_in (256 KiB) | Wt_out (128 KiB) | yb (64 MiB) | xb (64 MiB)
  unsigned short* wtin  = (unsigned short*)(ws);
  unsigned short* wtout = (unsigned short*)(ws + 262144);
  unsigned short* yb    = (unsigned short*)(ws + 393216);
  unsigned short* xb    = (unsigned short*)(ws + 393216 + (size_t)Mc * 256 * 2);

  cvt_x_k<<<1024, 256, 0, stream>>>(x, xb, Mc * 256);
  cvtW_k<<<768, 256, 0, stream>>>(Win, Wout, wtin, wtout);
  g1scan_k<<<256, 512, 0, stream>>>(xb, wtin, bin, yb);
  gemm2_k<<<2048, 256, 0, stream>>>(yb, wtout, bout, out);
}

// Round 11
// 188.612 us; speedup vs baseline: 1.0098x; 1.0032x over previous
//
#include <hip/hip_runtime.h>
#include <hip/hip_bf16.h>
#include <hip/hip_fp16.h>
#include <cstdint>

typedef __attribute__((ext_vector_type(4))) float f32x4;
typedef __attribute__((ext_vector_type(8))) short s16x8;

#define DEVI static __device__ __forceinline__

constexpr int Bc = 8, Tc = 2048, Sc = 8, Dc = 256;
constexpr int Mc = Bc * Tc * Sc;  // 131072 rows

// plain-cast f32->bf16 (RNE): compiler packs pairs into v_cvt_pk_bf16_f32
DEVI unsigned short f2bf(float x) {
  return __bfloat16_as_ushort(__float2bfloat16(x));
}

DEVI f32x4 mfma16(s16x8 a, s16x8 b, f32x4 c) {
  return __builtin_amdgcn_mfma_f32_16x16x32_bf16(a, b, c, 0, 0, 0);
}

// async global->LDS, 16B per lane (dest must be wave-uniform base + lane*16)
DEVI void gld16(const void* g, void* l) {
  __builtin_amdgcn_global_load_lds(
      (const __attribute__((address_space(1))) unsigned int*)g,
      (__attribute__((address_space(3))) unsigned int*)l, 16, 0, 0);
}

// ---------------- x f32 -> bf16 ----------------
__global__ void cvt_x_k(const float* __restrict__ in, unsigned short* __restrict__ out, int n) {
  int i = (blockIdx.x * blockDim.x + threadIdx.x) * 8;
  int stride = gridDim.x * blockDim.x * 8;
  for (; i < n; i += stride) {
    f32x4 a = *(const f32x4*)(in + i);
    f32x4 b = *(const f32x4*)(in + i + 4);
    s16x8 o;
    o[0] = (short)f2bf(a[0]); o[1] = (short)f2bf(a[1]);
    o[2] = (short)f2bf(a[2]); o[3] = (short)f2bf(a[3]);
    o[4] = (short)f2bf(b[0]); o[5] = (short)f2bf(b[1]);
    o[6] = (short)f2bf(b[2]); o[7] = (short)f2bf(b[3]);
    *(s16x8*)(out + i) = o;
  }
}

// ---------------- weight transpose+convert (both W in one kernel) ----------------
__global__ void cvtW_k(const float* __restrict__ Win, const float* __restrict__ Wout,
                       unsigned short* __restrict__ wtin, unsigned short* __restrict__ wtout) {
  int tid = blockIdx.x * blockDim.x + threadIdx.x;
  if (tid < 512 * 256) {
    int c = tid >> 8, r = tid & 255;
    wtin[tid] = f2bf(Win[r * 512 + c]);
  } else {
    int t = tid - 512 * 256;
    int c = t >> 8, r = t & 255;
    wtout[t] = f2bf(Wout[r * 256 + c]);
  }
}

// ---------------- fused GEMM1 + activation + parallel scan ----------------
// Block = (b, s, dq): 256 blocks x 512 threads (8 waves). LDS trimmed to 44 KB
// (W fragments in registers loaded straight from L2-resident global; CHUNK=32;
// abuf/seg single-buffered -- B1/B2 already separate their read/write phases)
// -> 2 blocks/CU: co-resident block absorbs barrier/drain stalls.
__global__ __launch_bounds__(512, 4) void g1scan_k(
    const unsigned short* __restrict__ xb,   // [M][256] bf16
    const unsigned short* __restrict__ wt,   // [512][256] bf16 = W_in^T
    const float* __restrict__ bias,          // [512]
    unsigned short* __restrict__ yb)         // [M][256] bf16
{
  __shared__ unsigned short As[2][8 * 32 * 32];   // 2 x 16 KB; [buf][kf][row][32]
  __shared__ unsigned int   abuf[32 * 64];        // 8 KB: [t_local][d_local]
  __shared__ float segA[8][64], segB[8][64];      // 4 KB

  int bid = blockIdx.x;
  int b = bid >> 5, s = (bid >> 2) & 7, dq = bid & 3;
  int tid = threadIdx.x;
  int lane = tid & 63, wave = tid >> 6;
  int rg = wave >> 2, cg = wave & 3;              // rg: row group (16 rows), cg: col group

  const short* xs = (const short*)xb;
  const short* wsrc = (const short*)wt;
  size_t rowbase = (size_t)b * 16384 + s;         // global row = rowbase + t*8

  int cl = cg * 16 + (lane & 15);                 // d-local col
  int kg = (lane >> 4) * 8;

  // ---- W fragments: global -> registers (one-time, L2-resident weights) ----
  s16x8 bGr[8], bCr[8];
  #pragma unroll
  for (int kf = 0; kf < 8; ++kf) {
    bGr[kf] = *(const s16x8*)(wsrc + (size_t)(dq * 64 + cl) * 256 + kf * 32 + kg);
    bCr[kf] = *(const s16x8*)(wsrc + (size_t)(256 + dq * 64 + cl) * 256 + kf * 32 + kg);
  }

  float bg = bias[dq * 64 + cl];
  float bc = bias[256 + dq * 64 + cl];

  // ---- incremental A-staging pointers: 1024 16B chunks/tile, 2 per thread ----
  // chunk j: kf = j>>7, row = (j&127)>>2, cc = j&3
  const short* pA[2];
  int ldso[2];
  #pragma unroll
  for (int q = 0; q < 2; ++q) {
    int j = q * 512 + tid;
    int kf = j >> 7, rem = j & 127, r = rem >> 2, cc = rem & 3;
    pA[q] = xs + (rowbase + (size_t)r * 8) * 256 + kf * 32 + cc * 8;
    ldso[q] = j * 8;
  }
  const size_t ASTRIDE = (size_t)32 * 8 * 256;    // shorts per 32-t chunk

  // prologue: stage chunks 0 and 1
  #pragma unroll
  for (int q = 0; q < 2; ++q) gld16(pA[q], (unsigned short*)As[0] + ldso[q]);
  #pragma unroll
  for (int q = 0; q < 2; ++q) gld16(pA[q] + ASTRIDE, (unsigned short*)As[1] + ldso[q]);
  #pragma unroll
  for (int q = 0; q < 2; ++q) pA[q] += 2 * ASTRIDE;

  float stt = 0.f;   // scan carry for d = dq*64 + lane (identical across waves)

  __syncthreads();   // drains prologue stages

  for (int ch = 0; ch < 64; ++ch) {
    int cur = ch & 1;
    const unsigned short* Ab = (const unsigned short*)As[cur];

    // ---- GEMM: 16 rows (rg) x 16 cols (cl), W from registers ----
    f32x4 accG = {}, accC = {};
    #pragma unroll
    for (int kf = 0; kf < 8; ++kf) {
      s16x8 aF = *(const s16x8*)(Ab + kf * 1024 + (rg * 16 + (lane & 15)) * 32 + kg);
      accG = mfma16(aF, bGr[kf], accG);
      accC = mfma16(aF, bCr[kf], accC);
    }

    // ---- activation in-register ----
    unsigned pk[4];
    #pragma unroll
    for (int r = 0; r < 4; ++r) {
      float g = accG[r] + bg;
      float c = accC[r] + bc;
      float alpha = 1.f / (1.f + __expf(-g));
      float e2 = __expf(2.f * c);
      float th = 1.f - 2.f / (e2 + 1.f);   // tanh(c), stable for +/-inf
      __half2 h;
      h.x = __float2half(1.f - alpha);
      h.y = __float2half(alpha * th);
      pk[r] = *(unsigned*)&h;
    }
    #pragma unroll
    for (int r = 0; r < 4; ++r) {
      int row = rg * 16 + (lane >> 4) * 4 + r;
      abuf[row * 64 + cl] = pk[r];
    }

    __syncthreads();   // B1: abuf ready (also drains stage issued last chunk)

    // ---- compose: wave w owns t-steps [w*4, w*4+4) ----
    float av[4], bv[4];
    float A = 1.f, Bv = 0.f;
    #pragma unroll
    for (int u = 0; u < 4; ++u) {
      unsigned vv = abuf[(wave * 4 + u) * 64 + lane];
      __half2 h = *(__half2*)&vv;
      av[u] = __half2float(h.x);
      bv[u] = __half2float(h.y);
      A = av[u] * A;
      Bv = fmaf(av[u], Bv, bv[u]);
    }
    segA[wave][lane] = A;
    segB[wave][lane] = Bv;

    __syncthreads();   // B2: segments ready

    // ---- issue chunk ch+2 staging (drained at NEXT chunk's B1) ----
    if (ch + 2 < 64) {
      #pragma unroll
      for (int q = 0; q < 2; ++q) gld16(pA[q], (unsigned short*)As[cur] + ldso[q]);
      #pragma unroll
      for (int q = 0; q < 2; ++q) pA[q] += ASTRIDE;
    }

    // ---- redundant prefix walk (identical on every wave) + apply ----
    float sin = stt, s_w = stt;
    #pragma unroll
    for (int w2 = 0; w2 < 8; ++w2) {
      if (w2 == wave) s_w = sin;
      sin = fmaf(segA[w2][lane], sin, segB[w2][lane]);
    }
    stt = sin;         // carry into next chunk

    size_t ybase = (rowbase + (size_t)(ch * 32 + wave * 4) * 8) * 256 + dq * 64 + lane;
    float sv = s_w;
    #pragma unroll
    for (int u = 0; u < 4; ++u) {
      sv = fmaf(av[u], sv, bv[u]);
      yb[ybase + (size_t)u * 8 * 256] = f2bf(sv);
    }
  }
}

// ---------------- GEMM2: out = y@W_out + b_out ----------------
// BK=64 as two [128][32] sub-panels. grid 2048 = 1024 mtiles x 2 ctiles.
__global__ __launch_bounds__(256, 2) void gemm2_k(
    const unsigned short* __restrict__ yb,   // [M][256] bf16
    const unsigned short* __restrict__ wt,   // [256][256] bf16 = W_out^T
    const float* __restrict__ bias,          // [256]
    float* __restrict__ out)
{
  __shared__ unsigned short As[2][2][128 * 32];
  __shared__ unsigned short Bs[2][2][128 * 32];

  int bid = blockIdx.x;
  int swz = (bid & 7) * 256 + (bid >> 3);
  int mtile = swz >> 1, ctile = swz & 1;
  int tid = threadIdx.x;
  int lane = tid & 63, wave = tid >> 6;
  int wr = wave >> 1, wc = wave & 1;

  const short* ys = (const short*)yb;
  const short* wsrc = (const short*)wt;

  auto STAGE = [&](int buf, int k0) {
    unsigned short* Ad = &As[buf][0][0];
    unsigned short* Bd = &Bs[buf][0][0];
    #pragma unroll
    for (int q = 0; q < 4; ++q) {
      int j = q * 256 + tid;
      int p = j >> 9, r = (j >> 2) & 127, cc = j & 3;
      int koff = k0 + p * 32 + cc * 8;
      gld16(ys + (size_t)(mtile * 128 + r) * 256 + koff, Ad + (size_t)j * 8);
      gld16(wsrc + (size_t)(ctile * 128 + r) * 256 + koff, Bd + (size_t)j * 8);
    }
  };

  f32x4 acc[4][4] = {};

  STAGE(0, 0);
  __syncthreads();
  #pragma unroll
  for (int kk = 0; kk < 4; ++kk) {
    int cur = kk & 1;
    if (kk < 3) STAGE(cur ^ 1, (kk + 1) * 64);
    int kg = (lane >> 4) * 8;
    #pragma unroll
    for (int ks = 0; ks < 2; ++ks) {
      s16x8 aF[4], bF[4];
      #pragma unroll
      for (int mf = 0; mf < 4; ++mf)
        aF[mf] = *(const s16x8*)&As[cur][ks][(wr * 64 + mf * 16 + (lane & 15)) * 32 + kg];
      #pragma unroll
      for (int nf = 0; nf < 4; ++nf)
        bF[nf] = *(const s16x8*)&Bs[cur][ks][(wc * 64 + nf * 16 + (lane & 15)) * 32 + kg];
      #pragma unroll
      for (int mf = 0; mf < 4; ++mf)
        #pragma unroll
        for (int nf = 0; nf < 4; ++nf)
          acc[mf][nf] = mfma16(aF[mf], bF[nf], acc[mf][nf]);
    }
    if (kk < 3) __syncthreads();
  }

  int orow0 = mtile * 128 + wr * 64 + (lane >> 4) * 4;
  #pragma unroll
  for (int nf = 0; nf < 4; ++nf) {
    int col = ctile * 128 + wc * 64 + nf * 16 + (lane & 15);
    float bo = bias[col];
    #pragma unroll
    for (int mf = 0; mf < 4; ++mf) {
      #pragma unroll
      for (int r = 0; r < 4; ++r) {
        int row = orow0 + mf * 16 + r;
        out[(size_t)row * 256 + col] = acc[mf][nf][r] + bo;
      }
    }
  }
}

// ---------------- host ----------------
extern "C" void kernel_launch(void* const* d_in, const int* in_sizes, int n_in,
                              void* d_out, int out_size, void* d_ws, size_t ws_size,
                              hipStream_t stream)
{
  const float* x    = (const float*)d_in[0];
  const float* Win  = (const float*)d_in[1];
  const float* bin  = (const float*)d_in[2];
  const float* Wout = (const float*)d_in[3];
  const float* bout = (const float*)d_in[4];
  float* out = (float*)d_out;
  char* ws = (char*)d_ws;

  // ws layout: Wt_in (256 KiB) | Wt_out (128 KiB) | yb (64 MiB) | xb (64 MiB)
  unsigned short* wtin  = (unsigned short*)(ws);
  unsigned short* wtout = (unsigned short*)(ws + 262144);
  unsigned short* yb    = (unsigned short*)(ws + 393216);
  unsigned short* xb    = (unsigned short*)(ws + 393216 + (size_t)Mc * 256 * 2);

  cvt_x_k<<<1024, 256, 0, stream>>>(x, xb, Mc * 256);
  cvtW_k<<<768, 256, 0, stream>>>(Win, Wout, wtin, wtout);
  g1scan_k<<<256, 512, 0, stream>>>(xb, wtin, bin, yb);
  gemm2_k<<<2048, 256, 0, stream>>>(yb, wtout, bout, out);
}

// Round 12
// 181.622 us; speedup vs baseline: 1.0487x; 1.0385x over previous
//
#include <hip/hip_runtime.h>
#include <hip/hip_bf16.h>
#include <hip/hip_fp16.h>
#include <cstdint>

typedef __attribute__((ext_vector_type(4))) float f32x4;
typedef __attribute__((ext_vector_type(8))) short s16x8;

#define DEVI static __device__ __forceinline__

constexpr int Bc = 8, Tc = 2048, Sc = 8, Dc = 256;
constexpr int Mc = Bc * Tc * Sc;  // 131072 rows

// plain-cast f32->bf16 (RNE): compiler packs pairs into v_cvt_pk_bf16_f32
DEVI unsigned short f2bf(float x) {
  return __bfloat16_as_ushort(__float2bfloat16(x));
}

DEVI f32x4 mfma16(s16x8 a, s16x8 b, f32x4 c) {
  return __builtin_amdgcn_mfma_f32_16x16x32_bf16(a, b, c, 0, 0, 0);
}

// async global->LDS, 16B per lane (dest must be wave-uniform base + lane*16)
DEVI void gld16(const void* g, void* l) {
  __builtin_amdgcn_global_load_lds(
      (const __attribute__((address_space(1))) unsigned int*)g,
      (__attribute__((address_space(3))) unsigned int*)l, 16, 0, 0);
}

// ---------------- x f32 -> bf16 ----------------
__global__ void cvt_x_k(const float* __restrict__ in, unsigned short* __restrict__ out, int n) {
  int i = (blockIdx.x * blockDim.x + threadIdx.x) * 8;
  int stride = gridDim.x * blockDim.x * 8;
  for (; i < n; i += stride) {
    f32x4 a = *(const f32x4*)(in + i);
    f32x4 b = *(const f32x4*)(in + i + 4);
    s16x8 o;
    o[0] = (short)f2bf(a[0]); o[1] = (short)f2bf(a[1]);
    o[2] = (short)f2bf(a[2]); o[3] = (short)f2bf(a[3]);
    o[4] = (short)f2bf(b[0]); o[5] = (short)f2bf(b[1]);
    o[6] = (short)f2bf(b[2]); o[7] = (short)f2bf(b[3]);
    *(s16x8*)(out + i) = o;
  }
}

// ---------------- weight transpose+convert (both W in one kernel) ----------------
__global__ void cvtW_k(const float* __restrict__ Win, const float* __restrict__ Wout,
                       unsigned short* __restrict__ wtin, unsigned short* __restrict__ wtout) {
  int tid = blockIdx.x * blockDim.x + threadIdx.x;
  if (tid < 512 * 256) {
    int c = tid >> 8, r = tid & 255;
    wtin[tid] = f2bf(Win[r * 512 + c]);
  } else {
    int t = tid - 512 * 256;
    int c = t >> 8, r = t & 255;
    wtout[t] = f2bf(Wout[r * 256 + c]);
  }
}

// ---------------- fused GEMM1 + activation + parallel scan ----------------
// GRID 512 (= 2 blocks/CU; r11 showed grid=256=CU-count capped occupancy at 1
// block/CU and was the real constraint). Block = (b, s, dq) with dq = 8 slices
// of 32 d-cols; 512 threads (8 waves = 4 row-groups x 2 col-groups); chunk =
// 64 t-steps; compose/prefix over 16 segments of 4 (all lanes busy). XCD
// swizzle gives each XCD one batch b -> x fetched ~once per XCD L2.
// LDS 76 KB -> 2 blocks/CU.
__global__ __launch_bounds__(512, 2) void g1scan_k(
    const unsigned short* __restrict__ xb,   // [M][256] bf16
    const unsigned short* __restrict__ wt,   // [512][256] bf16 = W_in^T
    const float* __restrict__ bias,          // [512]
    unsigned short* __restrict__ yb)         // [M][256] bf16
{
  __shared__ unsigned short As[2][8 * 64 * 32];   // 2 x 32 KB; [buf][kf][row64][32]
  __shared__ unsigned int   abuf[64 * 32];        // 8 KB: [t_local][d_local]
  __shared__ float segA[16][32], segB[16][32];    // 4 KB

  int bid = blockIdx.x;
  int lb = (bid & 7) * 64 + (bid >> 3);           // XCD x owns batch b = x
  int b = lb >> 6, s = (lb >> 3) & 7, dq = lb & 7;
  int tid = threadIdx.x;
  int lane = tid & 63, wave = tid >> 6;
  int rg = wave >> 1, cg = wave & 1;              // 4 row-groups x 2 col-groups

  const short* xs = (const short*)xb;
  const short* wsrc = (const short*)wt;
  size_t rowbase = (size_t)b * 16384 + s;         // global row = rowbase + t*8

  int cl = cg * 16 + (lane & 15);                 // d-local col in [0,32)
  int kg = (lane >> 4) * 8;

  // ---- W fragments: global -> registers (one-time, L2-resident weights) ----
  s16x8 bGr[8], bCr[8];
  #pragma unroll
  for (int kf = 0; kf < 8; ++kf) {
    bGr[kf] = *(const s16x8*)(wsrc + (size_t)(dq * 32 + cl) * 256 + kf * 32 + kg);
    bCr[kf] = *(const s16x8*)(wsrc + (size_t)(256 + dq * 32 + cl) * 256 + kf * 32 + kg);
  }
  float bg = bias[dq * 32 + cl];
  float bc = bias[256 + dq * 32 + cl];

  // ---- incremental A-staging pointers: 2048 16B chunks/tile, 4 per thread ----
  // chunk j: kf = j>>8, row = (j&255)>>2, cc = j&3
  const short* pA[4];
  int ldso[4];
  #pragma unroll
  for (int q = 0; q < 4; ++q) {
    int j = q * 512 + tid;
    int kf = j >> 8, rem = j & 255, r = rem >> 2, cc = rem & 3;
    pA[q] = xs + (rowbase + (size_t)r * 8) * 256 + kf * 32 + cc * 8;
    ldso[q] = j * 8;
  }
  const size_t ASTRIDE = (size_t)64 * 8 * 256;    // shorts per 64-t chunk

  // prologue: stage chunks 0 and 1
  #pragma unroll
  for (int q = 0; q < 4; ++q) gld16(pA[q], (unsigned short*)As[0] + ldso[q]);
  #pragma unroll
  for (int q = 0; q < 4; ++q) gld16(pA[q] + ASTRIDE, (unsigned short*)As[1] + ldso[q]);
  #pragma unroll
  for (int q = 0; q < 4; ++q) pA[q] += 2 * ASTRIDE;

  float stt = 0.f;   // scan carry for d = dq*32 + (lane&31) (same across waves)

  __syncthreads();   // drains prologue stages

  for (int ch = 0; ch < 32; ++ch) {
    int cur = ch & 1;
    const unsigned short* Ab = (const unsigned short*)As[cur];

    // ---- GEMM: 16 rows (rg) x 16 cols (cg), W from registers ----
    f32x4 accG = {}, accC = {};
    #pragma unroll
    for (int kf = 0; kf < 8; ++kf) {
      s16x8 aF = *(const s16x8*)(Ab + kf * 2048 + (rg * 16 + (lane & 15)) * 32 + kg);
      accG = mfma16(aF, bGr[kf], accG);
      accC = mfma16(aF, bCr[kf], accC);
    }

    // ---- activation in-register ----
    unsigned pk[4];
    #pragma unroll
    for (int r = 0; r < 4; ++r) {
      float g = accG[r] + bg;
      float c = accC[r] + bc;
      float alpha = 1.f / (1.f + __expf(-g));
      float e2 = __expf(2.f * c);
      float th = 1.f - 2.f / (e2 + 1.f);   // tanh(c), stable for +/-inf
      __half2 h;
      h.x = __float2half(1.f - alpha);
      h.y = __float2half(alpha * th);
      pk[r] = *(unsigned*)&h;
    }
    #pragma unroll
    for (int r = 0; r < 4; ++r) {
      int trow = rg * 16 + (lane >> 4) * 4 + r;
      abuf[trow * 32 + cl] = pk[r];
    }

    __syncthreads();   // B1: abuf ready (also drains stage issued last chunk)

    // ---- compose: segment sid = wave*2 + (lane>>5) owns t [sid*4, sid*4+4) ----
    int sid = wave * 2 + (lane >> 5), dd = lane & 31;
    float av[4], bv[4];
    float A = 1.f, Bv = 0.f;
    #pragma unroll
    for (int u = 0; u < 4; ++u) {
      unsigned vv = abuf[(sid * 4 + u) * 32 + dd];
      __half2 h = *(__half2*)&vv;
      av[u] = __half2float(h.x);
      bv[u] = __half2float(h.y);
      A = av[u] * A;
      Bv = fmaf(av[u], Bv, bv[u]);
    }
    segA[sid][dd] = A;
    segB[sid][dd] = Bv;

    __syncthreads();   // B2: segments ready

    // ---- issue chunk ch+2 staging (drained at NEXT chunk's B1) ----
    if (ch + 2 < 32) {
      #pragma unroll
      for (int q = 0; q < 4; ++q) gld16(pA[q], (unsigned short*)As[cur] + ldso[q]);
      #pragma unroll
      for (int q = 0; q < 4; ++q) pA[q] += ASTRIDE;
    }

    // ---- redundant prefix walk (identical on every wave) + apply ----
    float sin = stt, s_w = stt;
    #pragma unroll
    for (int w2 = 0; w2 < 16; ++w2) {
      if (w2 == sid) s_w = sin;
      sin = fmaf(segA[w2][dd], sin, segB[w2][dd]);
    }
    stt = sin;         // carry into next chunk

    size_t ybase = (rowbase + (size_t)(ch * 64 + sid * 4) * 8) * 256 + dq * 32 + dd;
    float sv = s_w;
    #pragma unroll
    for (int u = 0; u < 4; ++u) {
      sv = fmaf(av[u], sv, bv[u]);
      yb[ybase + (size_t)u * 8 * 256] = f2bf(sv);
    }
  }
}

// ---------------- GEMM2: out = y@W_out + b_out ----------------
// BK=64 as two [128][32] sub-panels. grid 2048 = 1024 mtiles x 2 ctiles.
__global__ __launch_bounds__(256, 2) void gemm2_k(
    const unsigned short* __restrict__ yb,   // [M][256] bf16
    const unsigned short* __restrict__ wt,   // [256][256] bf16 = W_out^T
    const float* __restrict__ bias,          // [256]
    float* __restrict__ out)
{
  __shared__ unsigned short As[2][2][128 * 32];
  __shared__ unsigned short Bs[2][2][128 * 32];

  int bid = blockIdx.x;
  int swz = (bid & 7) * 256 + (bid >> 3);
  int mtile = swz >> 1, ctile = swz & 1;
  int tid = threadIdx.x;
  int lane = tid & 63, wave = tid >> 6;
  int wr = wave >> 1, wc = wave & 1;

  const short* ys = (const short*)yb;
  const short* wsrc = (const short*)wt;

  auto STAGE = [&](int buf, int k0) {
    unsigned short* Ad = &As[buf][0][0];
    unsigned short* Bd = &Bs[buf][0][0];
    #pragma unroll
    for (int q = 0; q < 4; ++q) {
      int j = q * 256 + tid;
      int p = j >> 9, r = (j >> 2) & 127, cc = j & 3;
      int koff = k0 + p * 32 + cc * 8;
      gld16(ys + (size_t)(mtile * 128 + r) * 256 + koff, Ad + (size_t)j * 8);
      gld16(wsrc + (size_t)(ctile * 128 + r) * 256 + koff, Bd + (size_t)j * 8);
    }
  };

  f32x4 acc[4][4] = {};

  STAGE(0, 0);
  __syncthreads();
  #pragma unroll
  for (int kk = 0; kk < 4; ++kk) {
    int cur = kk & 1;
    if (kk < 3) STAGE(cur ^ 1, (kk + 1) * 64);
    int kg = (lane >> 4) * 8;
    #pragma unroll
    for (int ks = 0; ks < 2; ++ks) {
      s16x8 aF[4], bF[4];
      #pragma unroll
      for (int mf = 0; mf < 4; ++mf)
        aF[mf] = *(const s16x8*)&As[cur][ks][(wr * 64 + mf * 16 + (lane & 15)) * 32 + kg];
      #pragma unroll
      for (int nf = 0; nf < 4; ++nf)
        bF[nf] = *(const s16x8*)&Bs[cur][ks][(wc * 64 + nf * 16 + (lane & 15)) * 32 + kg];
      #pragma unroll
      for (int mf = 0; mf < 4; ++mf)
        #pragma unroll
        for (int nf = 0; nf < 4; ++nf)
          acc[mf][nf] = mfma16(aF[mf], bF[nf], acc[mf][nf]);
    }
    if (kk < 3) __syncthreads();
  }

  int orow0 = mtile * 128 + wr * 64 + (lane >> 4) * 4;
  #pragma unroll
  for (int nf = 0; nf < 4; ++nf) {
    int col = ctile * 128 + wc * 64 + nf * 16 + (lane & 15);
    float bo = bias[col];
    #pragma unroll
    for (int mf = 0; mf < 4; ++mf) {
      #pragma unroll
      for (int r = 0; r < 4; ++r) {
        int row = orow0 + mf * 16 + r;
        out[(size_t)row * 256 + col] = acc[mf][nf][r] + bo;
      }
    }
  }
}

// ---------------- host ----------------
extern "C" void kernel_launch(void* const* d_in, const int* in_sizes, int n_in,
                              void* d_out, int out_size, void* d_ws, size_t ws_size,
                              hipStream_t stream)
{
  const float* x    = (const float*)d_in[0];
  const float* Win  = (const float*)d_in[1];
  const float* bin  = (const float*)d_in[2];
  const float* Wout = (const float*)d_in[3];
  const float* bout = (const float*)d_in[4];
  float* out = (float*)d_out;
  char* ws = (char*)d_ws;

  // ws layout: Wt_in (256 KiB) | Wt_out (128 KiB) | yb (64 MiB) | xb (64 MiB)
  unsigned short* wtin  = (unsigned short*)(ws);
  unsigned short* wtout = (unsigned short*)(ws + 262144);
  unsigned short* yb    = (unsigned short*)(ws + 393216);
  unsigned short* xb    = (unsigned short*)(ws + 393216 + (size_t)Mc * 256 * 2);

  cvt_x_k<<<1024, 256, 0, stream>>>(x, xb, Mc * 256);
  cvtW_k<<<768, 256, 0, stream>>>(Win, Wout, wtin, wtout);
  g1scan_k<<<512, 512, 0, stream>>>(xb, wtin, bin, yb);
  gemm2_k<<<2048, 256, 0, stream>>>(yb, wtout, bout, out);
}

// Round 13
// 172.533 us; speedup vs baseline: 1.1039x; 1.0527x over previous
//
#include <hip/hip_runtime.h>
#include <hip/hip_bf16.h>
#include <hip/hip_fp16.h>
#include <cstdint>

typedef __attribute__((ext_vector_type(4))) float f32x4;
typedef __attribute__((ext_vector_type(8))) short s16x8;

#define DEVI static __device__ __forceinline__

constexpr int Bc = 8, Tc = 2048, Sc = 8, Dc = 256;
constexpr int Mc = Bc * Tc * Sc;  // 131072 rows

// plain-cast f32->bf16 (RNE): compiler packs pairs into v_cvt_pk_bf16_f32
DEVI unsigned short f2bf(float x) {
  return __bfloat16_as_ushort(__float2bfloat16(x));
}

DEVI f32x4 mfma16(s16x8 a, s16x8 b, f32x4 c) {
  return __builtin_amdgcn_mfma_f32_16x16x32_bf16(a, b, c, 0, 0, 0);
}

// async global->LDS, 16B per lane (dest must be wave-uniform base + lane*16)
DEVI void gld16(const void* g, void* l) {
  __builtin_amdgcn_global_load_lds(
      (const __attribute__((address_space(1))) unsigned int*)g,
      (__attribute__((address_space(3))) unsigned int*)l, 16, 0, 0);
}

// ---------------- x f32 -> bf16 ----------------
__global__ void cvt_x_k(const float* __restrict__ in, unsigned short* __restrict__ out, int n) {
  int i = (blockIdx.x * blockDim.x + threadIdx.x) * 8;
  int stride = gridDim.x * blockDim.x * 8;
  for (; i < n; i += stride) {
    f32x4 a = *(const f32x4*)(in + i);
    f32x4 b = *(const f32x4*)(in + i + 4);
    s16x8 o;
    o[0] = (short)f2bf(a[0]); o[1] = (short)f2bf(a[1]);
    o[2] = (short)f2bf(a[2]); o[3] = (short)f2bf(a[3]);
    o[4] = (short)f2bf(b[0]); o[5] = (short)f2bf(b[1]);
    o[6] = (short)f2bf(b[2]); o[7] = (short)f2bf(b[3]);
    *(s16x8*)(out + i) = o;
  }
}

// ---------------- weight transpose+convert (both W in one kernel) ----------------
__global__ void cvtW_k(const float* __restrict__ Win, const float* __restrict__ Wout,
                       unsigned short* __restrict__ wtin, unsigned short* __restrict__ wtout) {
  int tid = blockIdx.x * blockDim.x + threadIdx.x;
  if (tid < 512 * 256) {
    int c = tid >> 8, r = tid & 255;
    wtin[tid] = f2bf(Win[r * 512 + c]);
  } else {
    int t = tid - 512 * 256;
    int c = t >> 8, r = t & 255;
    wtout[t] = f2bf(Wout[r * 256 + c]);
  }
}

// ---------------- fused GEMM1 + activation + scan (1 barrier/chunk) ----------------
// Grid 512 = (b,s,dq), dq = 8 slices of 32 d-cols; 512 threads = 4 rg x 2 cg.
// MFMA C-layout puts 4 consecutive t of one d-col in each thread (row=hi*4+r,
// col=lo), and hi-groups are consecutive t-segments -> scan composition is done
// per-thread + 2x __shfl_up in-wave prefix; only 128 (A,B) wave-segments touch
// LDS (1KB, dbuf). abuf + second barrier DELETED. One barrier/chunk protects
// As dbuf, publishes segs, drains prefetch.
__global__ __launch_bounds__(512, 2) void g1scan_k(
    const unsigned short* __restrict__ xb,   // [M][256] bf16
    const unsigned short* __restrict__ wt,   // [512][256] bf16 = W_in^T
    const float* __restrict__ bias,          // [512]
    unsigned short* __restrict__ yb)         // [M][256] bf16
{
  __shared__ unsigned short As[2][8 * 64 * 32];   // 2 x 32 KB; [buf][kf][row64][32]
  __shared__ float segA[2][4][32], segB[2][4][32]; // 2 KB wave-segment pairs

  int bid = blockIdx.x;
  int lb = (bid & 7) * 64 + (bid >> 3);           // XCD x owns batch b = x
  int b = lb >> 6, s = (lb >> 3) & 7, dq = lb & 7;
  int tid = threadIdx.x;
  int lane = tid & 63, wave = tid >> 6;
  int rg = wave >> 1, cg = wave & 1;              // 4 t-row groups x 2 col groups
  int lo = lane & 15, hi = lane >> 4;

  const short* xs = (const short*)xb;
  const short* wsrc = (const short*)wt;
  size_t rowbase = (size_t)b * 16384 + s;         // global row = rowbase + t*8

  int cl = cg * 16 + lo;                          // d-local col in [0,32)
  int kg = hi * 8;

  // ---- W fragments: global -> registers (one-time, L2-resident weights) ----
  s16x8 bGr[8], bCr[8];
  #pragma unroll
  for (int kf = 0; kf < 8; ++kf) {
    bGr[kf] = *(const s16x8*)(wsrc + (size_t)(dq * 32 + cl) * 256 + kf * 32 + kg);
    bCr[kf] = *(const s16x8*)(wsrc + (size_t)(256 + dq * 32 + cl) * 256 + kf * 32 + kg);
  }
  float bg = bias[dq * 32 + cl];
  float bc = bias[256 + dq * 32 + cl];

  // ---- incremental A-staging pointers: 2048 16B chunks/tile, 4 per thread ----
  const short* pA[4];
  int ldso[4];
  #pragma unroll
  for (int q = 0; q < 4; ++q) {
    int j = q * 512 + tid;
    int kf = j >> 8, rem = j & 255, r = rem >> 2, cc = j & 3;
    pA[q] = xs + (rowbase + (size_t)r * 8) * 256 + kf * 32 + cc * 8;
    ldso[q] = j * 8;
  }
  const size_t ASTRIDE = (size_t)64 * 8 * 256;    // shorts per 64-t chunk

  // prologue: stage chunks 0 and 1
  #pragma unroll
  for (int q = 0; q < 4; ++q) gld16(pA[q], (unsigned short*)As[0] + ldso[q]);
  #pragma unroll
  for (int q = 0; q < 4; ++q) gld16(pA[q] + ASTRIDE, (unsigned short*)As[1] + ldso[q]);
  #pragma unroll
  for (int q = 0; q < 4; ++q) pA[q] += 2 * ASTRIDE;

  float stt = 0.f;   // block scan carry (identical across all threads of same d)

  __syncthreads();   // drains prologue stages

  for (int ch = 0; ch < 32; ++ch) {
    int cur = ch & 1;
    const unsigned short* Ab = (const unsigned short*)As[cur];

    // ---- GEMM: this thread ends with t = ch*64 + rg*16 + hi*4 + [0,4), d = cl ----
    f32x4 accG = {}, accC = {};
    #pragma unroll
    for (int kf = 0; kf < 8; ++kf) {
      s16x8 aF = *(const s16x8*)(Ab + kf * 2048 + (rg * 16 + lo) * 32 + kg);
      accG = mfma16(aF, bGr[kf], accG);
      accC = mfma16(aF, bCr[kf], accC);
    }

    // ---- activation in-register (f32, no fp16 round-trip) ----
    float av[4], bv[4];
    #pragma unroll
    for (int r = 0; r < 4; ++r) {
      float g = accG[r] + bg;
      float c = accC[r] + bc;
      float alpha = 1.f / (1.f + __expf(-g));
      float e2 = __expf(2.f * c);
      float th = 1.f - 2.f / (e2 + 1.f);   // tanh(c), stable for +/-inf
      av[r] = 1.f - alpha;
      bv[r] = alpha * th;
    }

    // ---- per-thread compose over its 4 t-steps ----
    float iA = av[0], iB = bv[0];
    #pragma unroll
    for (int r = 1; r < 4; ++r) { iA = iA * av[r]; iB = fmaf(av[r], iB, bv[r]); }

    // ---- in-wave inclusive prefix over hi (4 groups, lanes lo..lo+48) ----
    {
      float tA = __shfl_up(iA, 16), tB = __shfl_up(iB, 16);
      float nA = tA * iA, nB = fmaf(iA, tB, iB);
      if (hi >= 1) { iA = nA; iB = nB; }
      tA = __shfl_up(iA, 32); tB = __shfl_up(iB, 32);
      nA = tA * iA; nB = fmaf(iA, tB, iB);
      if (hi >= 2) { iA = nA; iB = nB; }
    }
    // exclusive-within-wave for this thread
    float eA = __shfl_up(iA, 16), eB = __shfl_up(iB, 16);
    if (hi == 0) { eA = 1.f; eB = 0.f; }
    // publish wave segment (inclusive at hi==3)
    if (hi == 3) { segA[cur][rg][cl] = iA; segB[cur][rg][cl] = iB; }

    __syncthreads();   // THE barrier: As dbuf + segs + drains stage(ch+1)

    // ---- issue chunk ch+2 staging into the just-freed buffer ----
    if (ch + 2 < 32) {
      #pragma unroll
      for (int q = 0; q < 4; ++q) gld16(pA[q], (unsigned short*)As[cur] + ldso[q]);
      #pragma unroll
      for (int q = 0; q < 4; ++q) pA[q] += ASTRIDE;
    }

    // ---- cross-wave walk over 4 rg segments (redundant, identical per d) ----
    float run = stt, s_w = stt;
    #pragma unroll
    for (int r2 = 0; r2 < 4; ++r2) {
      if (r2 == rg) s_w = run;
      run = fmaf(segA[cur][r2][cl], run, segB[cur][r2][cl]);
    }
    stt = run;                            // carry into next chunk

    // ---- apply: start = excl-wave o carry, then own 4 steps + store ----
    float sv = fmaf(eA, s_w, eB);
    size_t ybase = (rowbase + (size_t)(ch * 64 + rg * 16 + hi * 4) * 8) * 256 + dq * 32 + cl;
    #pragma unroll
    for (int u = 0; u < 4; ++u) {
      sv = fmaf(av[u], sv, bv[u]);
      yb[ybase + (size_t)u * 8 * 256] = f2bf(sv);
    }
  }
}

// ---------------- GEMM2: out = y@W_out + b_out ----------------
// BK=64 as two [128][32] sub-panels. grid 2048 = 1024 mtiles x 2 ctiles.
__global__ __launch_bounds__(256, 2) void gemm2_k(
    const unsigned short* __restrict__ yb,   // [M][256] bf16
    const unsigned short* __restrict__ wt,   // [256][256] bf16 = W_out^T
    const float* __restrict__ bias,          // [256]
    float* __restrict__ out)
{
  __shared__ unsigned short As[2][2][128 * 32];
  __shared__ unsigned short Bs[2][2][128 * 32];

  int bid = blockIdx.x;
  int swz = (bid & 7) * 256 + (bid >> 3);
  int mtile = swz >> 1, ctile = swz & 1;
  int tid = threadIdx.x;
  int lane = tid & 63, wave = tid >> 6;
  int wr = wave >> 1, wc = wave & 1;

  const short* ys = (const short*)yb;
  const short* wsrc = (const short*)wt;

  auto STAGE = [&](int buf, int k0) {
    unsigned short* Ad = &As[buf][0][0];
    unsigned short* Bd = &Bs[buf][0][0];
    #pragma unroll
    for (int q = 0; q < 4; ++q) {
      int j = q * 256 + tid;
      int p = j >> 9, r = (j >> 2) & 127, cc = j & 3;
      int koff = k0 + p * 32 + cc * 8;
      gld16(ys + (size_t)(mtile * 128 + r) * 256 + koff, Ad + (size_t)j * 8);
      gld16(wsrc + (size_t)(ctile * 128 + r) * 256 + koff, Bd + (size_t)j * 8);
    }
  };

  f32x4 acc[4][4] = {};

  STAGE(0, 0);
  __syncthreads();
  #pragma unroll
  for (int kk = 0; kk < 4; ++kk) {
    int cur = kk & 1;
    if (kk < 3) STAGE(cur ^ 1, (kk + 1) * 64);
    int kg = (lane >> 4) * 8;
    #pragma unroll
    for (int ks = 0; ks < 2; ++ks) {
      s16x8 aF[4], bF[4];
      #pragma unroll
      for (int mf = 0; mf < 4; ++mf)
        aF[mf] = *(const s16x8*)&As[cur][ks][(wr * 64 + mf * 16 + (lane & 15)) * 32 + kg];
      #pragma unroll
      for (int nf = 0; nf < 4; ++nf)
        bF[nf] = *(const s16x8*)&Bs[cur][ks][(wc * 64 + nf * 16 + (lane & 15)) * 32 + kg];
      #pragma unroll
      for (int mf = 0; mf < 4; ++mf)
        #pragma unroll
        for (int nf = 0; nf < 4; ++nf)
          acc[mf][nf] = mfma16(aF[mf], bF[nf], acc[mf][nf]);
    }
    if (kk < 3) __syncthreads();
  }

  int orow0 = mtile * 128 + wr * 64 + (lane >> 4) * 4;
  #pragma unroll
  for (int nf = 0; nf < 4; ++nf) {
    int col = ctile * 128 + wc * 64 + nf * 16 + (lane & 15);
    float bo = bias[col];
    #pragma unroll
    for (int mf = 0; mf < 4; ++mf) {
      #pragma unroll
      for (int r = 0; r < 4; ++r) {
        int row = orow0 + mf * 16 + r;
        out[(size_t)row * 256 + col] = acc[mf][nf][r] + bo;
      }
    }
  }
}

// ---------------- host ----------------
extern "C" void kernel_launch(void* const* d_in, const int* in_sizes, int n_in,
                              void* d_out, int out_size, void* d_ws, size_t ws_size,
                              hipStream_t stream)
{
  const float* x    = (const float*)d_in[0];
  const float* Win  = (const float*)d_in[1];
  const float* bin  = (const float*)d_in[2];
  const float* Wout = (const float*)d_in[3];
  const float* bout = (const float*)d_in[4];
  float* out = (float*)d_out;
  char* ws = (char*)d_ws;

  // ws layout: Wt_in (256 KiB) | Wt_out (128 KiB) | yb (64 MiB) | xb (64 MiB)
  unsigned short* wtin  = (unsigned short*)(ws);
  unsigned short* wtout = (unsigned short*)(ws + 262144);
  unsigned short* yb    = (unsigned short*)(ws + 393216);
  unsigned short* xb    = (unsigned short*)(ws + 393216 + (size_t)Mc * 256 * 2);

  cvt_x_k<<<1024, 256, 0, stream>>>(x, xb, Mc * 256);
  cvtW_k<<<768, 256, 0, stream>>>(Win, Wout, wtin, wtout);
  g1scan_k<<<512, 512, 0, stream>>>(xb, wtin, bin, yb);
  gemm2_k<<<2048, 256, 0, stream>>>(yb, wtout, bout, out);
}